// Round 1
// 2339.344 us; speedup vs baseline: 1.3145x; 1.3145x over previous
//
#include <hip/hip_runtime.h>
#include <math.h>

#define B_  4
#define S_  2048
#define D_  1024
#define H_  16
#define DH_ 64
#define M_  (B_*S_)          // 8192
#define LN_EPS 1e-6f

typedef __attribute__((ext_vector_type(4))) float f32x4;
typedef __attribute__((ext_vector_type(8))) short s16x8;   // 8 bf16 = 4 VGPRs

// ---------------- fp32 -> bf16(hi) + bf16(lo) split (truncation) ------------
// hi = top 16 bits of x; r = x - hi (exact); lo = top 16 bits of r.
// Reconstruction error per element < 2^-16 relative -> bf16x3 GEMM ~ fp32.
__device__ __forceinline__ void split2(float x, ushort& h, ushort& l) {
  unsigned u = __float_as_uint(x);
  h = (ushort)(u >> 16);
  float r = x - __uint_as_float(u & 0xFFFF0000u);   // exact
  l = (ushort)(__float_as_uint(r) >> 16);
}

// Elementwise split: in [n] fp32 -> hi,lo [n] bf16. 8 elems/thread.
__global__ __launch_bounds__(256) void split_kernel(
    const float* __restrict__ in, ushort* __restrict__ hi, ushort* __restrict__ lo)
{
  const size_t t = (size_t)blockIdx.x * 256 + threadIdx.x;
  const float4 a = *(const float4*)(in + t * 8);
  const float4 b = *(const float4*)(in + t * 8 + 4);
  s16x8 hv, lv;
  ushort h, l;
  split2(a.x, h, l); hv[0] = (short)h; lv[0] = (short)l;
  split2(a.y, h, l); hv[1] = (short)h; lv[1] = (short)l;
  split2(a.z, h, l); hv[2] = (short)h; lv[2] = (short)l;
  split2(a.w, h, l); hv[3] = (short)h; lv[3] = (short)l;
  split2(b.x, h, l); hv[4] = (short)h; lv[4] = (short)l;
  split2(b.y, h, l); hv[5] = (short)h; lv[5] = (short)l;
  split2(b.z, h, l); hv[6] = (short)h; lv[6] = (short)l;
  split2(b.w, h, l); hv[7] = (short)h; lv[7] = (short)l;
  *(s16x8*)(hi + t * 8) = hv;
  *(s16x8*)(lo + t * 8) = lv;
}

// Transpose + split: W [K=1024][N=1024] fp32 -> hiT,loT [N][K] bf16.
__global__ __launch_bounds__(256) void splitT_kernel(
    const float* __restrict__ W, ushort* __restrict__ hiT, ushort* __restrict__ loT)
{
  __shared__ float tile[64][65];
  const int n0 = blockIdx.x * 64, k0 = blockIdx.y * 64;
  const int tid = threadIdx.x;
  #pragma unroll
  for (int i = 0; i < 4; ++i) {
    int c = tid + (i << 8);
    int r = c >> 4;              // k-local
    int c4 = (c & 15) << 2;      // n-local
    float4 v = *(const float4*)(W + (size_t)(k0 + r) * D_ + n0 + c4);
    tile[r][c4+0] = v.x; tile[r][c4+1] = v.y; tile[r][c4+2] = v.z; tile[r][c4+3] = v.w;
  }
  __syncthreads();
  #pragma unroll
  for (int i = 0; i < 4; ++i) {
    int c = tid + (i << 8);
    int n = c >> 4;              // n-local
    int k4 = (c & 15) << 2;      // k-local
    ushort h0,h1,h2,h3, l0,l1,l2,l3;
    split2(tile[k4+0][n], h0, l0);
    split2(tile[k4+1][n], h1, l1);
    split2(tile[k4+2][n], h2, l2);
    split2(tile[k4+3][n], h3, l3);
    size_t o = (size_t)(n0 + n) * D_ + k0 + k4;
    *(ushort4*)(hiT + o) = make_ushort4(h0, h1, h2, h3);
    *(ushort4*)(loT + o) = make_ushort4(l0, l1, l2, l3);
  }
}

// ---------------- bf16x3 MFMA GEMM: C = A@B + bias (+resid) -----------------
// A as Ahi/Alo [M][K] bf16; B as BThi/BTlo [N][K] bf16 (pre-transposed).
// Tile 128x128, BK=32, 4 waves (2x2), each wave 64x64 via 4x4 frags of 16x16.
// Fragment k-placement: lane holds k = (lane>>4)*8 .. +8 contiguous, identical
// for A and B (layout-permutation-safe). C/D: col=lane&15, row=(lane>>4)*4+j.
#define LDK 40   // padded LDS row (bf16 elems): 80 B stride -> <=2-way banks

__global__ __launch_bounds__(256) void gemm_mfma_kernel(
    const ushort* __restrict__ Ahi, const ushort* __restrict__ Alo,
    const ushort* __restrict__ BThi, const ushort* __restrict__ BTlo,
    const float* __restrict__ bias, const float* __restrict__ resid,
    float* __restrict__ C, int M, int N, int K)
{
  __shared__ ushort Ah[128][LDK];
  __shared__ ushort Al[128][LDK];
  __shared__ ushort Bh[128][LDK];
  __shared__ ushort Bl[128][LDK];
  const int tid  = threadIdx.x;
  const int lane = tid & 63;
  const int wid  = tid >> 6;
  const int wm   = wid >> 1, wn = wid & 1;
  const int bm = blockIdx.y * 128, bn = blockIdx.x * 128;

  // staging: 512 chunks of 8 bf16 per matrix-part, 2 chunks/thread
  const int c0 = tid,       r0 = c0 >> 2, k80 = (c0 & 3) << 3;
  const int c1 = tid + 256, r1 = c1 >> 2, k81 = (c1 & 3) << 3;

  f32x4 acc[4][4] = {};

  const int kf = (lane >> 4) << 3;          // 0,8,16,24
  const int fm = wm * 64 + (lane & 15);
  const int fn = wn * 64 + (lane & 15);

  for (int k0 = 0; k0 < K; k0 += 32) {
    const size_t ga0 = (size_t)(bm + r0) * K + k0 + k80;
    const size_t ga1 = (size_t)(bm + r1) * K + k0 + k81;
    const size_t gb0 = (size_t)(bn + r0) * K + k0 + k80;
    const size_t gb1 = (size_t)(bn + r1) * K + k0 + k81;
    s16x8 va0 = *(const s16x8*)(Ahi  + ga0);
    s16x8 va1 = *(const s16x8*)(Ahi  + ga1);
    s16x8 ua0 = *(const s16x8*)(Alo  + ga0);
    s16x8 ua1 = *(const s16x8*)(Alo  + ga1);
    s16x8 vb0 = *(const s16x8*)(BThi + gb0);
    s16x8 vb1 = *(const s16x8*)(BThi + gb1);
    s16x8 ub0 = *(const s16x8*)(BTlo + gb0);
    s16x8 ub1 = *(const s16x8*)(BTlo + gb1);
    *(s16x8*)&Ah[r0][k80] = va0;  *(s16x8*)&Ah[r1][k81] = va1;
    *(s16x8*)&Al[r0][k80] = ua0;  *(s16x8*)&Al[r1][k81] = ua1;
    *(s16x8*)&Bh[r0][k80] = vb0;  *(s16x8*)&Bh[r1][k81] = vb1;
    *(s16x8*)&Bl[r0][k80] = ub0;  *(s16x8*)&Bl[r1][k81] = ub1;
    __syncthreads();
    s16x8 ah[4], al[4], bh[4], bl[4];
    #pragma unroll
    for (int i = 0; i < 4; ++i) {
      ah[i] = *(const s16x8*)&Ah[fm + i*16][kf];
      al[i] = *(const s16x8*)&Al[fm + i*16][kf];
      bh[i] = *(const s16x8*)&Bh[fn + i*16][kf];
      bl[i] = *(const s16x8*)&Bl[fn + i*16][kf];
    }
    #pragma unroll
    for (int mi = 0; mi < 4; ++mi) {
      #pragma unroll
      for (int ni = 0; ni < 4; ++ni) {
        acc[mi][ni] = __builtin_amdgcn_mfma_f32_16x16x32_bf16(ah[mi], bh[ni], acc[mi][ni], 0, 0, 0);
        acc[mi][ni] = __builtin_amdgcn_mfma_f32_16x16x32_bf16(al[mi], bh[ni], acc[mi][ni], 0, 0, 0);
        acc[mi][ni] = __builtin_amdgcn_mfma_f32_16x16x32_bf16(ah[mi], bl[ni], acc[mi][ni], 0, 0, 0);
      }
    }
    __syncthreads();
  }
  // epilogue: C/D layout col=lane&15, row=(lane>>4)*4+j  [m89/m91-verified]
  const int rbase = bm + wm*64 + ((lane >> 4) << 2);
  #pragma unroll
  for (int ni = 0; ni < 4; ++ni) {
    const int col = bn + wn*64 + ni*16 + (lane & 15);
    const float bb = bias[col];
    #pragma unroll
    for (int mi = 0; mi < 4; ++mi) {
      #pragma unroll
      for (int j = 0; j < 4; ++j) {
        const int row = rbase + mi*16 + j;
        float v = acc[mi][ni][j] + bb;
        if (resid) v += resid[(size_t)row * N + col];
        C[(size_t)row * N + col] = v;
      }
    }
  }
}

// ---------------- block-wide all-reduce (256 threads = 4 waves of 64) -------
__device__ __forceinline__ float block_allreduce(float v, bool is_max, float* sbuf) {
  #pragma unroll
  for (int o = 32; o > 0; o >>= 1) {
    float other = __shfl_down(v, o, 64);
    v = is_max ? fmaxf(v, other) : (v + other);
  }
  __syncthreads();                       // protect sbuf reuse across calls
  if ((threadIdx.x & 63) == 0) sbuf[threadIdx.x >> 6] = v;
  __syncthreads();
  float r = sbuf[0];
  #pragma unroll
  for (int w = 1; w < 4; ++w) r = is_max ? fmaxf(r, sbuf[w]) : (r + sbuf[w]);
  return r;
}

// ---------------- scores: raw causal scores into weights buffer -------------
__global__ __launch_bounds__(256) void scores_kernel(
    const float* __restrict__ Q, const float* __restrict__ Km,
    float* __restrict__ Wout)
{
  const int kt = blockIdx.x, qt = blockIdx.y;
  if (kt > qt) return;                       // fully-masked tile
  const int bh = blockIdx.z;
  const int b = bh >> 4, h = bh & 15;
  const int q0 = qt * 64, k0 = kt * 64;
  __shared__ float Qs[64][68];   // [q][d]
  __shared__ float Ks[64][68];   // [d][k]  (transposed)
  const int tid = threadIdx.x;
  const int tx = tid & 15, ty = tid >> 4;
  const float* Qbase = Q  + ((size_t)b * S_ + q0) * D_ + h * DH_;
  const float* Kbase = Km + ((size_t)b * S_ + k0) * D_ + h * DH_;
  #pragma unroll
  for (int i = 0; i < 4; ++i) {
    int idx = tid + i * 256;
    int r = idx >> 4;            // 0..63
    int c4 = (idx & 15) << 2;    // 0..60
    float4 qv = *(const float4*)(Qbase + (size_t)r * D_ + c4);
    *(float4*)(&Qs[r][c4]) = qv;
    float4 kv = *(const float4*)(Kbase + (size_t)r * D_ + c4);
    Ks[c4+0][r] = kv.x; Ks[c4+1][r] = kv.y; Ks[c4+2][r] = kv.z; Ks[c4+3][r] = kv.w;
  }
  __syncthreads();
  float acc[4][4] = {};
  #pragma unroll 8
  for (int d = 0; d < 64; ++d) {
    float4 kv = *(float4*)(&Ks[d][tx*4]);
    float a0 = Qs[ty*4+0][d], a1 = Qs[ty*4+1][d];
    float a2 = Qs[ty*4+2][d], a3 = Qs[ty*4+3][d];
    acc[0][0] += a0*kv.x; acc[0][1] += a0*kv.y; acc[0][2] += a0*kv.z; acc[0][3] += a0*kv.w;
    acc[1][0] += a1*kv.x; acc[1][1] += a1*kv.y; acc[1][2] += a1*kv.z; acc[1][3] += a1*kv.w;
    acc[2][0] += a2*kv.x; acc[2][1] += a2*kv.y; acc[2][2] += a2*kv.z; acc[2][3] += a2*kv.w;
    acc[3][0] += a3*kv.x; acc[3][1] += a3*kv.y; acc[3][2] += a3*kv.z; acc[3][3] += a3*kv.w;
  }
  const float scale = 0.125f;   // 1/sqrt(64)
  float* Wrow = Wout + ((size_t)bh * S_ + q0) * S_ + k0;
  if (kt < qt) {                // fully unmasked tile
    #pragma unroll
    for (int i = 0; i < 4; ++i) {
      float4 o;
      o.x = acc[i][0]*scale; o.y = acc[i][1]*scale;
      o.z = acc[i][2]*scale; o.w = acc[i][3]*scale;
      *(float4*)(Wrow + (size_t)(ty*4+i) * S_ + tx*4) = o;
    }
  } else {                      // diagonal tile: per-element causal guard
    #pragma unroll
    for (int i = 0; i < 4; ++i) {
      int qg = q0 + ty*4 + i;
      #pragma unroll
      for (int j = 0; j < 4; ++j) {
        int kg = k0 + tx*4 + j;
        if (kg <= qg) Wrow[(size_t)(ty*4+i) * S_ + tx*4 + j] = acc[i][j] * scale;
      }
    }
  }
}

// ---------------- softmax: in-place over each row, zeros above diagonal -----
__global__ __launch_bounds__(256) void softmax_kernel(float* __restrict__ Wbuf) {
  const int q = blockIdx.x;
  float* row = Wbuf + ((size_t)blockIdx.y * S_ + q) * S_;
  const int valid = q + 1;
  __shared__ float sbuf[4];
  float v[8];
  float lmax = -INFINITY;
  #pragma unroll
  for (int i = 0; i < 8; ++i) {
    int k = threadIdx.x + (i << 8);
    v[i] = (k < valid) ? row[k] : -INFINITY;
    lmax = fmaxf(lmax, v[i]);
  }
  float m = block_allreduce(lmax, true, sbuf);
  float lsum = 0.f;
  #pragma unroll
  for (int i = 0; i < 8; ++i) {
    int k = threadIdx.x + (i << 8);
    v[i] = (k < valid) ? __expf(v[i] - m) : 0.f;   // masked -> exactly 0
    lsum += v[i];
  }
  float s = block_allreduce(lsum, false, sbuf);
  float inv = 1.f / s;
  #pragma unroll
  for (int i = 0; i < 8; ++i) {
    int k = threadIdx.x + (i << 8);
    row[k] = v[i] * inv;
  }
}

// ---------------- PV: attn[b,q,h,:] = sum_k W[b,h,q,k] * V[b,k,h,:] ---------
__global__ __launch_bounds__(256) void pv_kernel(
    const float* __restrict__ Wbuf, const float* __restrict__ V,
    float* __restrict__ Attn)
{
  const int qt = blockIdx.x, h = blockIdx.y, b = blockIdx.z;
  const int q0 = qt * 64;
  __shared__ float Ws[64][68];   // [q][k]
  __shared__ float Vs[64][68];   // [k][d]
  const int tid = threadIdx.x;
  const int tx = tid & 15, ty = tid >> 4;
  float acc[4][4] = {};
  const size_t wbase = (((size_t)b * H_ + h) * S_ + q0) * S_;
  const float* Vbase = V + (size_t)b * S_ * D_ + h * DH_;
  for (int kt = 0; kt <= qt; ++kt) {       // causal: masked weights are exactly 0
    int k0 = kt * 64;
    #pragma unroll
    for (int i = 0; i < 4; ++i) {
      int idx = tid + i * 256;
      int r = idx >> 4, c4 = (idx & 15) << 2;
      *(float4*)(&Ws[r][c4]) = *(const float4*)(Wbuf + wbase + (size_t)r * S_ + k0 + c4);
      *(float4*)(&Vs[r][c4]) = *(const float4*)(Vbase + (size_t)(k0 + r) * D_ + c4);
    }
    __syncthreads();
    #pragma unroll 8
    for (int kk = 0; kk < 64; ++kk) {
      float4 vv = *(float4*)(&Vs[kk][tx*4]);
      float w0 = Ws[ty*4+0][kk], w1 = Ws[ty*4+1][kk];
      float w2 = Ws[ty*4+2][kk], w3 = Ws[ty*4+3][kk];
      acc[0][0] += w0*vv.x; acc[0][1] += w0*vv.y; acc[0][2] += w0*vv.z; acc[0][3] += w0*vv.w;
      acc[1][0] += w1*vv.x; acc[1][1] += w1*vv.y; acc[1][2] += w1*vv.z; acc[1][3] += w1*vv.w;
      acc[2][0] += w2*vv.x; acc[2][1] += w2*vv.y; acc[2][2] += w2*vv.z; acc[2][3] += w2*vv.w;
      acc[3][0] += w3*vv.x; acc[3][1] += w3*vv.y; acc[3][2] += w3*vv.z; acc[3][3] += w3*vv.w;
    }
    __syncthreads();
  }
  #pragma unroll
  for (int i = 0; i < 4; ++i) {
    float4 o = { acc[i][0], acc[i][1], acc[i][2], acc[i][3] };
    *(float4*)(Attn + ((size_t)b * S_ + q0 + ty*4 + i) * D_ + h * DH_ + tx*4) = o;
  }
}

// ---------------- LayerNorm over last dim (1024) ----------------------------
__global__ __launch_bounds__(256) void ln_kernel(
    const float* __restrict__ R, const float* __restrict__ gamma,
    const float* __restrict__ beta, float* __restrict__ Out)
{
  const int row = blockIdx.x;
  const float* x = R + (size_t)row * D_;
  __shared__ float sbuf[4];
  float4 xv = *(const float4*)(x + threadIdx.x * 4);
  float s  = xv.x + xv.y + xv.z + xv.w;
  float ss = xv.x*xv.x + xv.y*xv.y + xv.z*xv.z + xv.w*xv.w;
  float tot  = block_allreduce(s,  false, sbuf);
  float tot2 = block_allreduce(ss, false, sbuf);
  float mu  = tot  * (1.f / D_);
  float var = tot2 * (1.f / D_) - mu * mu;
  float inv = rsqrtf(var + LN_EPS);
  float4 g  = *(const float4*)(gamma + threadIdx.x * 4);
  float4 be = *(const float4*)(beta  + threadIdx.x * 4);
  float4 o;
  o.x = (xv.x - mu) * inv * g.x + be.x;
  o.y = (xv.y - mu) * inv * g.y + be.y;
  o.z = (xv.z - mu) * inv * g.z + be.z;
  o.w = (xv.w - mu) * inv * g.w + be.w;
  *(float4*)(Out + (size_t)row * D_ + threadIdx.x * 4) = o;
}

extern "C" void kernel_launch(void* const* d_in, const int* in_sizes, int n_in,
                              void* d_out, int out_size, void* d_ws, size_t ws_size,
                              hipStream_t stream) {
  const float* X     = (const float*)d_in[0];
  const float* Wq    = (const float*)d_in[1];
  const float* bq    = (const float*)d_in[2];
  const float* Wk    = (const float*)d_in[3];
  const float* bk    = (const float*)d_in[4];
  const float* Wv    = (const float*)d_in[5];
  const float* bv    = (const float*)d_in[6];
  const float* Wo    = (const float*)d_in[7];
  const float* bo    = (const float*)d_in[8];
  const float* gamma = (const float*)d_in[9];
  const float* beta  = (const float*)d_in[10];

  float* out     = (float*)d_out;
  float* normed  = out;
  float* weights = out + (size_t)B_ * S_ * D_;       // [B,H,S,S]

  const size_t sz = (size_t)B_ * S_ * D_;            // 8388608 floats
  const size_t wsz = (size_t)D_ * D_;                // 1048576
  float* ws   = (float*)d_ws;
  float* Qb   = ws;
  float* Kb   = ws + sz;
  float* Vb   = ws + 2 * sz;
  float* Attn  = Qb;   // Q dead after scores
  float* Resid = Kb;   // K dead after scores

  // Phase-1 bf16 scratch lives in the weights output region (fully
  // overwritten later by scores+softmax, which rewrite every byte).
  ushort* Xhi  = (ushort*)weights;
  ushort* Xlo  = Xhi + sz;
  ushort* WqHi = Xlo + sz;      ushort* WqLo = WqHi + wsz;
  ushort* WkHi = WqLo + wsz;    ushort* WkLo = WkHi + wsz;
  ushort* WvHi = WkLo + wsz;    ushort* WvLo = WvHi + wsz;
  // Late-phase scratch in ws: V dead after pv; Attn fp32 dead after its split.
  ushort* AtHi = (ushort*)Vb;   ushort* AtLo = AtHi + sz;
  ushort* WoHi = (ushort*)Qb;   ushort* WoLo = WoHi + wsz;

  dim3 blk(256);
  dim3 gg(D_ / 128, M_ / 128);                       // (8, 64)
  dim3 sg(sz / 2048);                                // 4096: 8 elems/thread

  split_kernel <<<sg, blk, 0, stream>>>(X, Xhi, Xlo);
  splitT_kernel<<<dim3(16,16), blk, 0, stream>>>(Wq, WqHi, WqLo);
  splitT_kernel<<<dim3(16,16), blk, 0, stream>>>(Wk, WkHi, WkLo);
  splitT_kernel<<<dim3(16,16), blk, 0, stream>>>(Wv, WvHi, WvLo);

  gemm_mfma_kernel<<<gg, blk, 0, stream>>>(Xhi, Xlo, WqHi, WqLo, bq, nullptr, Qb, M_, D_, D_);
  gemm_mfma_kernel<<<gg, blk, 0, stream>>>(Xhi, Xlo, WkHi, WkLo, bk, nullptr, Kb, M_, D_, D_);
  gemm_mfma_kernel<<<gg, blk, 0, stream>>>(Xhi, Xlo, WvHi, WvLo, bv, nullptr, Vb, M_, D_, D_);

  scores_kernel<<<dim3(S_/64, S_/64, B_*H_), blk, 0, stream>>>(Qb, Kb, weights);
  softmax_kernel<<<dim3(S_, B_*H_), blk, 0, stream>>>(weights);
  pv_kernel<<<dim3(S_/64, H_, B_), blk, 0, stream>>>(weights, Vb, Attn);

  split_kernel <<<sg, blk, 0, stream>>>(Attn, AtHi, AtLo);       // -> Vb region
  splitT_kernel<<<dim3(16,16), blk, 0, stream>>>(Wo, WoHi, WoLo);// -> Qb region
  gemm_mfma_kernel<<<gg, blk, 0, stream>>>(AtHi, AtLo, WoHi, WoLo, bo, X, Resid, M_, D_, D_);

  ln_kernel<<<dim3(M_), blk, 0, stream>>>(Resid, gamma, beta, normed);
}

// Round 2
// 2122.482 us; speedup vs baseline: 1.4488x; 1.1022x over previous
//
#include <hip/hip_runtime.h>
#include <math.h>

#define B_  4
#define S_  2048
#define D_  1024
#define H_  16
#define DH_ 64
#define M_  (B_*S_)          // 8192
#define LN_EPS 1e-6f

typedef __attribute__((ext_vector_type(4))) float f32x4;
typedef __attribute__((ext_vector_type(8))) short s16x8;   // 8 bf16 = 4 VGPRs

// ---------------- fp32 -> bf16(hi) + bf16(lo) split (truncation) ------------
__device__ __forceinline__ void split2(float x, ushort& h, ushort& l) {
  unsigned u = __float_as_uint(x);
  h = (ushort)(u >> 16);
  float r = x - __uint_as_float(u & 0xFFFF0000u);   // exact
  l = (ushort)(__float_as_uint(r) >> 16);
}

// Elementwise split: in [n] fp32 -> hi,lo [n] bf16. 8 elems/thread.
__global__ __launch_bounds__(256) void split_kernel(
    const float* __restrict__ in, ushort* __restrict__ hi, ushort* __restrict__ lo)
{
  const size_t t = (size_t)blockIdx.x * 256 + threadIdx.x;
  const float4 a = *(const float4*)(in + t * 8);
  const float4 b = *(const float4*)(in + t * 8 + 4);
  s16x8 hv, lv;
  ushort h, l;
  split2(a.x, h, l); hv[0] = (short)h; lv[0] = (short)l;
  split2(a.y, h, l); hv[1] = (short)h; lv[1] = (short)l;
  split2(a.z, h, l); hv[2] = (short)h; lv[2] = (short)l;
  split2(a.w, h, l); hv[3] = (short)h; lv[3] = (short)l;
  split2(b.x, h, l); hv[4] = (short)h; lv[4] = (short)l;
  split2(b.y, h, l); hv[5] = (short)h; lv[5] = (short)l;
  split2(b.z, h, l); hv[6] = (short)h; lv[6] = (short)l;
  split2(b.w, h, l); hv[7] = (short)h; lv[7] = (short)l;
  *(s16x8*)(hi + t * 8) = hv;
  *(s16x8*)(lo + t * 8) = lv;
}

// Transpose + split: W [K=1024][N=1024] fp32 -> hiT,loT [N][K] bf16.
__global__ __launch_bounds__(256) void splitT_kernel(
    const float* __restrict__ W, ushort* __restrict__ hiT, ushort* __restrict__ loT)
{
  __shared__ float tile[64][65];
  const int n0 = blockIdx.x * 64, k0 = blockIdx.y * 64;
  const int tid = threadIdx.x;
  #pragma unroll
  for (int i = 0; i < 4; ++i) {
    int c = tid + (i << 8);
    int r = c >> 4;
    int c4 = (c & 15) << 2;
    float4 v = *(const float4*)(W + (size_t)(k0 + r) * D_ + n0 + c4);
    tile[r][c4+0] = v.x; tile[r][c4+1] = v.y; tile[r][c4+2] = v.z; tile[r][c4+3] = v.w;
  }
  __syncthreads();
  #pragma unroll
  for (int i = 0; i < 4; ++i) {
    int c = tid + (i << 8);
    int n = c >> 4;
    int k4 = (c & 15) << 2;
    ushort h0,h1,h2,h3, l0,l1,l2,l3;
    split2(tile[k4+0][n], h0, l0);
    split2(tile[k4+1][n], h1, l1);
    split2(tile[k4+2][n], h2, l2);
    split2(tile[k4+3][n], h3, l3);
    size_t o = (size_t)(n0 + n) * D_ + k0 + k4;
    *(ushort4*)(hiT + o) = make_ushort4(h0, h1, h2, h3);
    *(ushort4*)(loT + o) = make_ushort4(l0, l1, l2, l3);
  }
}

// ---------------- bf16x3 MFMA GEMM: C = A@B + bias (+resid) -----------------
#define LDK 40   // padded LDS row (bf16 elems): 80 B stride -> <=2-way banks

__global__ __launch_bounds__(256) void gemm_mfma_kernel(
    const ushort* __restrict__ Ahi, const ushort* __restrict__ Alo,
    const ushort* __restrict__ BThi, const ushort* __restrict__ BTlo,
    const float* __restrict__ bias, const float* __restrict__ resid,
    float* __restrict__ C, int M, int N, int K)
{
  __shared__ ushort Ah[128][LDK];
  __shared__ ushort Al[128][LDK];
  __shared__ ushort Bh[128][LDK];
  __shared__ ushort Bl[128][LDK];
  const int tid  = threadIdx.x;
  const int lane = tid & 63;
  const int wid  = tid >> 6;
  const int wm   = wid >> 1, wn = wid & 1;
  const int bm = blockIdx.y * 128, bn = blockIdx.x * 128;

  const int c0 = tid,       r0 = c0 >> 2, k80 = (c0 & 3) << 3;
  const int c1 = tid + 256, r1 = c1 >> 2, k81 = (c1 & 3) << 3;

  f32x4 acc[4][4] = {};

  const int kf = (lane >> 4) << 3;
  const int fm = wm * 64 + (lane & 15);
  const int fn = wn * 64 + (lane & 15);

  for (int k0 = 0; k0 < K; k0 += 32) {
    const size_t ga0 = (size_t)(bm + r0) * K + k0 + k80;
    const size_t ga1 = (size_t)(bm + r1) * K + k0 + k81;
    const size_t gb0 = (size_t)(bn + r0) * K + k0 + k80;
    const size_t gb1 = (size_t)(bn + r1) * K + k0 + k81;
    s16x8 va0 = *(const s16x8*)(Ahi  + ga0);
    s16x8 va1 = *(const s16x8*)(Ahi  + ga1);
    s16x8 ua0 = *(const s16x8*)(Alo  + ga0);
    s16x8 ua1 = *(const s16x8*)(Alo  + ga1);
    s16x8 vb0 = *(const s16x8*)(BThi + gb0);
    s16x8 vb1 = *(const s16x8*)(BThi + gb1);
    s16x8 ub0 = *(const s16x8*)(BTlo + gb0);
    s16x8 ub1 = *(const s16x8*)(BTlo + gb1);
    *(s16x8*)&Ah[r0][k80] = va0;  *(s16x8*)&Ah[r1][k81] = va1;
    *(s16x8*)&Al[r0][k80] = ua0;  *(s16x8*)&Al[r1][k81] = ua1;
    *(s16x8*)&Bh[r0][k80] = vb0;  *(s16x8*)&Bh[r1][k81] = vb1;
    *(s16x8*)&Bl[r0][k80] = ub0;  *(s16x8*)&Bl[r1][k81] = ub1;
    __syncthreads();
    s16x8 ah[4], al[4], bh[4], bl[4];
    #pragma unroll
    for (int i = 0; i < 4; ++i) {
      ah[i] = *(const s16x8*)&Ah[fm + i*16][kf];
      al[i] = *(const s16x8*)&Al[fm + i*16][kf];
      bh[i] = *(const s16x8*)&Bh[fn + i*16][kf];
      bl[i] = *(const s16x8*)&Bl[fn + i*16][kf];
    }
    #pragma unroll
    for (int mi = 0; mi < 4; ++mi) {
      #pragma unroll
      for (int ni = 0; ni < 4; ++ni) {
        acc[mi][ni] = __builtin_amdgcn_mfma_f32_16x16x32_bf16(ah[mi], bh[ni], acc[mi][ni], 0, 0, 0);
        acc[mi][ni] = __builtin_amdgcn_mfma_f32_16x16x32_bf16(al[mi], bh[ni], acc[mi][ni], 0, 0, 0);
        acc[mi][ni] = __builtin_amdgcn_mfma_f32_16x16x32_bf16(ah[mi], bl[ni], acc[mi][ni], 0, 0, 0);
      }
    }
    __syncthreads();
  }
  const int rbase = bm + wm*64 + ((lane >> 4) << 2);
  #pragma unroll
  for (int ni = 0; ni < 4; ++ni) {
    const int col = bn + wn*64 + ni*16 + (lane & 15);
    const float bb = bias[col];
    #pragma unroll
    for (int mi = 0; mi < 4; ++mi) {
      #pragma unroll
      for (int j = 0; j < 4; ++j) {
        const int row = rbase + mi*16 + j;
        float v = acc[mi][ni][j] + bb;
        if (resid) v += resid[(size_t)row * N + col];
        C[(size_t)row * N + col] = v;
      }
    }
  }
}

// ---------------- block-wide all-reduce (256 threads = 4 waves of 64) -------
__device__ __forceinline__ float block_allreduce(float v, bool is_max, float* sbuf) {
  #pragma unroll
  for (int o = 32; o > 0; o >>= 1) {
    float other = __shfl_down(v, o, 64);
    v = is_max ? fmaxf(v, other) : (v + other);
  }
  __syncthreads();
  if ((threadIdx.x & 63) == 0) sbuf[threadIdx.x >> 6] = v;
  __syncthreads();
  float r = sbuf[0];
  #pragma unroll
  for (int w = 1; w < 4; ++w) r = is_max ? fmaxf(r, sbuf[w]) : (r + sbuf[w]);
  return r;
}

// ---------------- scores (MFMA bf16x3): causal raw scores -------------------
// Tile: 128 q x 64 k per block. Operands split in-kernel into LDS.
// Fragment/epilogue mapping identical to gemm_mfma_kernel (verified).
#define SQP 72   // 144B row stride -> <=2-way bank aliasing on frag reads

__global__ __launch_bounds__(256) void scores_mfma_kernel(
    const float* __restrict__ Q, const float* __restrict__ Km,
    float* __restrict__ Wout)
{
  const int kt = blockIdx.x;             // 0..31 (64-wide k tiles)
  const int qt = blockIdx.y;             // 0..15 (128-wide q tiles)
  if (kt > 2*qt + 1) return;             // fully masked
  const int bh = blockIdx.z;
  const int b = bh >> 4, h = bh & 15;
  const int q0 = qt * 128, k0 = kt * 64;
  __shared__ ushort Qh[128][SQP], Ql[128][SQP];
  __shared__ ushort Kh[64][SQP],  Kl[64][SQP];
  const int tid = threadIdx.x;
  const int lane = tid & 63, wid = tid >> 6;
  const int wm = wid >> 1, wn = wid & 1;   // wave tile: 64 q x 32 k
  const float* Qbase = Q  + ((size_t)b * S_ + q0) * D_ + h * DH_;
  const float* Kbase = Km + ((size_t)b * S_ + k0) * D_ + h * DH_;
  #pragma unroll
  for (int i = 0; i < 8; ++i) {          // Q: 128x64 fp32, 8 float4/thread
    int idx = tid + (i << 8);
    int r = idx >> 4, c4 = (idx & 15) << 2;
    float4 v = *(const float4*)(Qbase + (size_t)r * D_ + c4);
    ushort h0,h1,h2,h3,l0,l1,l2,l3;
    split2(v.x,h0,l0); split2(v.y,h1,l1); split2(v.z,h2,l2); split2(v.w,h3,l3);
    *(ushort4*)&Qh[r][c4] = make_ushort4(h0,h1,h2,h3);
    *(ushort4*)&Ql[r][c4] = make_ushort4(l0,l1,l2,l3);
  }
  #pragma unroll
  for (int i = 0; i < 4; ++i) {          // K: 64x64 fp32, 4 float4/thread
    int idx = tid + (i << 8);
    int r = idx >> 4, c4 = (idx & 15) << 2;
    float4 v = *(const float4*)(Kbase + (size_t)r * D_ + c4);
    ushort h0,h1,h2,h3,l0,l1,l2,l3;
    split2(v.x,h0,l0); split2(v.y,h1,l1); split2(v.z,h2,l2); split2(v.w,h3,l3);
    *(ushort4*)&Kh[r][c4] = make_ushort4(h0,h1,h2,h3);
    *(ushort4*)&Kl[r][c4] = make_ushort4(l0,l1,l2,l3);
  }
  __syncthreads();
  const int kf = (lane >> 4) << 3;
  const int fm = wm * 64 + (lane & 15);
  const int fn = wn * 32 + (lane & 15);
  f32x4 acc[4][2] = {};
  #pragma unroll
  for (int d0 = 0; d0 < 64; d0 += 32) {
    s16x8 qa[4], qb[4], ka[2], kb[2];
    #pragma unroll
    for (int mi = 0; mi < 4; ++mi) {
      qa[mi] = *(const s16x8*)&Qh[fm + mi*16][d0 + kf];
      qb[mi] = *(const s16x8*)&Ql[fm + mi*16][d0 + kf];
    }
    #pragma unroll
    for (int ni = 0; ni < 2; ++ni) {
      ka[ni] = *(const s16x8*)&Kh[fn + ni*16][d0 + kf];
      kb[ni] = *(const s16x8*)&Kl[fn + ni*16][d0 + kf];
    }
    #pragma unroll
    for (int mi = 0; mi < 4; ++mi) {
      #pragma unroll
      for (int ni = 0; ni < 2; ++ni) {
        acc[mi][ni] = __builtin_amdgcn_mfma_f32_16x16x32_bf16(qa[mi], ka[ni], acc[mi][ni], 0, 0, 0);
        acc[mi][ni] = __builtin_amdgcn_mfma_f32_16x16x32_bf16(qb[mi], ka[ni], acc[mi][ni], 0, 0, 0);
        acc[mi][ni] = __builtin_amdgcn_mfma_f32_16x16x32_bf16(qa[mi], kb[ni], acc[mi][ni], 0, 0, 0);
      }
    }
  }
  const float scale = 0.125f;   // 1/sqrt(64)
  float* Wrow = Wout + ((size_t)bh * S_ + q0) * S_ + k0;
  const int rb = wm*64 + ((lane >> 4) << 2);
  if ((kt >> 1) < qt) {          // fully unmasked tile
    #pragma unroll
    for (int ni = 0; ni < 2; ++ni) {
      const int col = wn*32 + ni*16 + (lane & 15);
      #pragma unroll
      for (int mi = 0; mi < 4; ++mi) {
        #pragma unroll
        for (int j = 0; j < 4; ++j)
          Wrow[(size_t)(rb + mi*16 + j) * S_ + col] = acc[mi][ni][j] * scale;
      }
    }
  } else {                       // diagonal-crossing tile: per-element guard
    #pragma unroll
    for (int ni = 0; ni < 2; ++ni) {
      const int col = wn*32 + ni*16 + (lane & 15);
      const int kg = k0 + col;
      #pragma unroll
      for (int mi = 0; mi < 4; ++mi) {
        #pragma unroll
        for (int j = 0; j < 4; ++j) {
          const int row = rb + mi*16 + j;
          if (kg <= q0 + row)
            Wrow[(size_t)row * S_ + col] = acc[mi][ni][j] * scale;
        }
      }
    }
  }
}

// ---------------- softmax: in-place over each row, zeros above diagonal -----
__global__ __launch_bounds__(256) void softmax_kernel(float* __restrict__ Wbuf) {
  const int q = blockIdx.x;
  float* row = Wbuf + ((size_t)blockIdx.y * S_ + q) * S_;
  const int valid = q + 1;
  __shared__ float sbuf[4];
  float v[8];
  float lmax = -INFINITY;
  #pragma unroll
  for (int i = 0; i < 8; ++i) {
    int k = threadIdx.x + (i << 8);
    v[i] = (k < valid) ? row[k] : -INFINITY;
    lmax = fmaxf(lmax, v[i]);
  }
  float m = block_allreduce(lmax, true, sbuf);
  float lsum = 0.f;
  #pragma unroll
  for (int i = 0; i < 8; ++i) {
    int k = threadIdx.x + (i << 8);
    v[i] = (k < valid) ? __expf(v[i] - m) : 0.f;
    lsum += v[i];
  }
  float s = block_allreduce(lsum, false, sbuf);
  float inv = 1.f / s;
  #pragma unroll
  for (int i = 0; i < 8; ++i) {
    int k = threadIdx.x + (i << 8);
    row[k] = v[i] * inv;
  }
}

// ---------------- PV (MFMA bf16x3): attn = W @ V per head -------------------
// Tile: 128 q x 64 d (full head) per block; loop k in 64-chunks (causal).
#define PVW 72   // W rows pad
#define PVV 74   // V^T rows pad (2-way on transposed scatter writes)

__global__ __launch_bounds__(256) void pv_mfma_kernel(
    const float* __restrict__ Wbuf, const float* __restrict__ V,
    float* __restrict__ Attn)
{
  const int qt = blockIdx.x, h = blockIdx.y, b = blockIdx.z;
  const int q0 = qt * 128;
  __shared__ ushort Wh[128][PVW], Wl[128][PVW];
  __shared__ ushort Vh[64][PVV],  Vl[64][PVV];
  const int tid = threadIdx.x;
  const int lane = tid & 63, wid = tid >> 6;
  const int wm = wid >> 1, wn = wid & 1;   // wave tile: 64 q x 32 d
  f32x4 acc[4][2] = {};
  const size_t wbase = (((size_t)b * H_ + h) * S_ + q0) * S_;
  const float* Vbase = V + (size_t)b * S_ * D_ + h * DH_;
  const int kf = (lane >> 4) << 3;
  const int fm = wm * 64 + (lane & 15);
  const int fn = wn * 32 + (lane & 15);
  const int nkt = 2*qt + 2;
  for (int kt = 0; kt < nkt; ++kt) {
    const int k0 = kt * 64;
    #pragma unroll
    for (int i = 0; i < 8; ++i) {        // W: 128 q x 64 k fp32
      int idx = tid + (i << 8);
      int r = idx >> 4, c4 = (idx & 15) << 2;
      float4 v = *(const float4*)(Wbuf + wbase + (size_t)r * S_ + k0 + c4);
      ushort h0,h1,h2,h3,l0,l1,l2,l3;
      split2(v.x,h0,l0); split2(v.y,h1,l1); split2(v.z,h2,l2); split2(v.w,h3,l3);
      *(ushort4*)&Wh[r][c4] = make_ushort4(h0,h1,h2,h3);
      *(ushort4*)&Wl[r][c4] = make_ushort4(l0,l1,l2,l3);
    }
    #pragma unroll
    for (int i = 0; i < 4; ++i) {        // V: 64 k x 64 d fp32 -> V^T[d][k]
      int idx = tid + (i << 8);
      int r = idx >> 4, c4 = (idx & 15) << 2;   // r=k-local, c4=d-local
      float4 v = *(const float4*)(Vbase + (size_t)(k0 + r) * D_ + c4);
      ushort h0,h1,h2,h3,l0,l1,l2,l3;
      split2(v.x,h0,l0); split2(v.y,h1,l1); split2(v.z,h2,l2); split2(v.w,h3,l3);
      Vh[c4+0][r] = h0; Vh[c4+1][r] = h1; Vh[c4+2][r] = h2; Vh[c4+3][r] = h3;
      Vl[c4+0][r] = l0; Vl[c4+1][r] = l1; Vl[c4+2][r] = l2; Vl[c4+3][r] = l3;
    }
    __syncthreads();
    #pragma unroll
    for (int kk = 0; kk < 64; kk += 32) {
      s16x8 wa[4], wb[4], va[2], vb[2];
      #pragma unroll
      for (int mi = 0; mi < 4; ++mi) {
        wa[mi] = *(const s16x8*)&Wh[fm + mi*16][kk + kf];
        wb[mi] = *(const s16x8*)&Wl[fm + mi*16][kk + kf];
      }
      #pragma unroll
      for (int ni = 0; ni < 2; ++ni) {
        va[ni] = *(const s16x8*)&Vh[fn + ni*16][kk + kf];
        vb[ni] = *(const s16x8*)&Vl[fn + ni*16][kk + kf];
      }
      #pragma unroll
      for (int mi = 0; mi < 4; ++mi) {
        #pragma unroll
        for (int ni = 0; ni < 2; ++ni) {
          acc[mi][ni] = __builtin_amdgcn_mfma_f32_16x16x32_bf16(wa[mi], va[ni], acc[mi][ni], 0, 0, 0);
          acc[mi][ni] = __builtin_amdgcn_mfma_f32_16x16x32_bf16(wb[mi], va[ni], acc[mi][ni], 0, 0, 0);
          acc[mi][ni] = __builtin_amdgcn_mfma_f32_16x16x32_bf16(wa[mi], vb[ni], acc[mi][ni], 0, 0, 0);
        }
      }
    }
    __syncthreads();
  }
  const int rb = q0 + wm*64 + ((lane >> 4) << 2);
  #pragma unroll
  for (int ni = 0; ni < 2; ++ni) {
    const int col = h * DH_ + wn*32 + ni*16 + (lane & 15);
    #pragma unroll
    for (int mi = 0; mi < 4; ++mi) {
      #pragma unroll
      for (int j = 0; j < 4; ++j)
        Attn[((size_t)b * S_ + rb + mi*16 + j) * D_ + col] = acc[mi][ni][j];
    }
  }
}

// ---------------- LayerNorm over last dim (1024) ----------------------------
__global__ __launch_bounds__(256) void ln_kernel(
    const float* __restrict__ R, const float* __restrict__ gamma,
    const float* __restrict__ beta, float* __restrict__ Out)
{
  const int row = blockIdx.x;
  const float* x = R + (size_t)row * D_;
  __shared__ float sbuf[4];
  float4 xv = *(const float4*)(x + threadIdx.x * 4);
  float s  = xv.x + xv.y + xv.z + xv.w;
  float ss = xv.x*xv.x + xv.y*xv.y + xv.z*xv.z + xv.w*xv.w;
  float tot  = block_allreduce(s,  false, sbuf);
  float tot2 = block_allreduce(ss, false, sbuf);
  float mu  = tot  * (1.f / D_);
  float var = tot2 * (1.f / D_) - mu * mu;
  float inv = rsqrtf(var + LN_EPS);
  float4 g  = *(const float4*)(gamma + threadIdx.x * 4);
  float4 be = *(const float4*)(beta  + threadIdx.x * 4);
  float4 o;
  o.x = (xv.x - mu) * inv * g.x + be.x;
  o.y = (xv.y - mu) * inv * g.y + be.y;
  o.z = (xv.z - mu) * inv * g.z + be.z;
  o.w = (xv.w - mu) * inv * g.w + be.w;
  *(float4*)(Out + (size_t)row * D_ + threadIdx.x * 4) = o;
}

extern "C" void kernel_launch(void* const* d_in, const int* in_sizes, int n_in,
                              void* d_out, int out_size, void* d_ws, size_t ws_size,
                              hipStream_t stream) {
  const float* X     = (const float*)d_in[0];
  const float* Wq    = (const float*)d_in[1];
  const float* bq    = (const float*)d_in[2];
  const float* Wk    = (const float*)d_in[3];
  const float* bk    = (const float*)d_in[4];
  const float* Wv    = (const float*)d_in[5];
  const float* bv    = (const float*)d_in[6];
  const float* Wo    = (const float*)d_in[7];
  const float* bo    = (const float*)d_in[8];
  const float* gamma = (const float*)d_in[9];
  const float* beta  = (const float*)d_in[10];

  float* out     = (float*)d_out;
  float* normed  = out;
  float* weights = out + (size_t)B_ * S_ * D_;       // [B,H,S,S]

  const size_t sz = (size_t)B_ * S_ * D_;            // 8388608 floats
  const size_t wsz = (size_t)D_ * D_;                // 1048576
  float* ws   = (float*)d_ws;
  float* Qb   = ws;
  float* Kb   = ws + sz;
  float* Vb   = ws + 2 * sz;
  float* Attn  = Qb;   // Q dead after scores
  float* Resid = Kb;   // K dead after scores

  // Phase-1 bf16 scratch lives in the weights output region (fully
  // overwritten later by scores+softmax, which rewrite every byte).
  ushort* Xhi  = (ushort*)weights;
  ushort* Xlo  = Xhi + sz;
  ushort* WqHi = Xlo + sz;      ushort* WqLo = WqHi + wsz;
  ushort* WkHi = WqLo + wsz;    ushort* WkLo = WkHi + wsz;
  ushort* WvHi = WkLo + wsz;    ushort* WvLo = WvHi + wsz;
  // Late-phase scratch in ws: V dead after pv; Attn fp32 dead after its split.
  ushort* AtHi = (ushort*)Vb;   ushort* AtLo = AtHi + sz;
  ushort* WoHi = (ushort*)Qb;   ushort* WoLo = WoHi + wsz;

  dim3 blk(256);
  dim3 gg(D_ / 128, M_ / 128);                       // (8, 64)
  dim3 sg(sz / 2048);                                // 4096: 8 elems/thread

  split_kernel <<<sg, blk, 0, stream>>>(X, Xhi, Xlo);
  splitT_kernel<<<dim3(16,16), blk, 0, stream>>>(Wq, WqHi, WqLo);
  splitT_kernel<<<dim3(16,16), blk, 0, stream>>>(Wk, WkHi, WkLo);
  splitT_kernel<<<dim3(16,16), blk, 0, stream>>>(Wv, WvHi, WvLo);

  gemm_mfma_kernel<<<gg, blk, 0, stream>>>(Xhi, Xlo, WqHi, WqLo, bq, nullptr, Qb, M_, D_, D_);
  gemm_mfma_kernel<<<gg, blk, 0, stream>>>(Xhi, Xlo, WkHi, WkLo, bk, nullptr, Kb, M_, D_, D_);
  gemm_mfma_kernel<<<gg, blk, 0, stream>>>(Xhi, Xlo, WvHi, WvLo, bv, nullptr, Vb, M_, D_, D_);

  scores_mfma_kernel<<<dim3(S_/64, S_/128, B_*H_), blk, 0, stream>>>(Qb, Kb, weights);
  softmax_kernel<<<dim3(S_, B_*H_), blk, 0, stream>>>(weights);
  pv_mfma_kernel<<<dim3(S_/128, H_, B_), blk, 0, stream>>>(weights, Vb, Attn);

  split_kernel <<<sg, blk, 0, stream>>>(Attn, AtHi, AtLo);       // -> Vb region
  splitT_kernel<<<dim3(16,16), blk, 0, stream>>>(Wo, WoHi, WoLo);// -> Qb region
  gemm_mfma_kernel<<<gg, blk, 0, stream>>>(AtHi, AtLo, WoHi, WoLo, bo, X, Resid, M_, D_, D_);

  ln_kernel<<<dim3(M_), blk, 0, stream>>>(Resid, gamma, beta, normed);
}